// Round 18
// baseline (129.229 us; speedup 1.0000x reference)
//
#include <hip/hip_runtime.h>
#include <hip/hip_fp16.h>

// Problem: B=2, H=8, L=2048, D=64.
// out0 = masked(p + p^T) @ v   (B,H,L,D)
// out1 = p + p^T               (B,H,L,L)
// p[b,h,qi,ki] += exp(-(q_sorted_r - k_sorted_r)^2)/D for rank-matched sorted
// q/k along L per (b,h,d). Each attn row receives exactly 64 direct + 64
// transpose entries (one per d) -> collision-free 4B slot per entry in the
// first 512B of each row's dense output region (u16 col | fp16 weight).
//
// R18 = R17 (127.6us) + (a) producer->consumer XCD alignment: prep's
// transpose/v16 blocks are remapped so the block that WRITES qT/kT/v16 for
// bh runs on the same XCD (bh/2) as the sort/row blocks that READ them ->
// local-L2 hits instead of L3 round-trips; (b) NT loads on read-once input
// streams (prep q/k/v, sort qT/kT) to avoid evicting the L2 write-combining
// working set. Placement/cache-policy only; no numerics change.

#define LSEQ 2048
#define DDIM 64
#define NBH  16
#define SNTHR 512
#define EPT  8   // elements per thread (per half) in sort
#define NPACKB 8192   // mask-pack blocks appended to sort grid (8 words each)

typedef float    f32x4 __attribute__((ext_vector_type(4)));
typedef unsigned u32x2 __attribute__((ext_vector_type(2)));

#define LGKM0() asm volatile("s_waitcnt lgkmcnt(0)" ::: "memory")

__device__ __forceinline__ unsigned long long pack_kv(float f, unsigned idx) {
  unsigned u = __float_as_uint(f);
  u = (u & 0x80000000u) ? ~u : (u | 0x80000000u);   // sortable-ascending
  return ((unsigned long long)u << 32) | idx;
}

__device__ __forceinline__ float unpack_val(unsigned long long p) {
  unsigned us = (unsigned)(p >> 32);
  unsigned u = (us & 0x80000000u) ? (us & 0x7fffffffu) : ~us;
  return __uint_as_float(u);
}

// lane-xor-1 / lane-xor-2 exchange via DPP quad_perm (VALU, no DS pipe).
template<int CTRL>
__device__ __forceinline__ unsigned long long dpp_swap(unsigned long long x) {
  int lo = __builtin_amdgcn_update_dpp(0, (int)(unsigned)x,         CTRL, 0xF, 0xF, true);
  int hi = __builtin_amdgcn_update_dpp(0, (int)(unsigned)(x >> 32), CTRL, 0xF, 0xF, true);
  return ((unsigned long long)(unsigned)hi << 32) | (unsigned)lo;
}

// ---- prep: blocks [0,512) transpose q,k -> [bh][D][L], XCD-aligned so the
//      writer runs on XCD bh/2 (same as the sort blocks that read it);
//      blocks [512, 512+1024) convert v f32 -> fp16, same alignment.
__global__ __launch_bounds__(256) void prep_kernel(
    const float* __restrict__ q, const float* __restrict__ k,
    float* __restrict__ qT, float* __restrict__ kT,
    const float* __restrict__ v, __half* __restrict__ v16) {
  const int t = threadIdx.x;
  if (blockIdx.x < 512) {
    __shared__ float tq[64][65], tk[64][65];
    // bid = xcd + 8*s, s in [0,64): bh = 2*xcd + (s>>5), chunk = s&31
    const int xcd = blockIdx.x & 7, s = blockIdx.x >> 3;
    const int bh = 2 * xcd + (s >> 5), chunk = s & 31;
    const size_t ib = (size_t)bh * LSEQ * DDIM + (size_t)chunk * 64 * DDIM;
    #pragma unroll
    for (int sp = 0; sp < 16; ++sp) {
      int i = t + sp * 256;             // 64(l) x 64(d) tile
      int l = i >> 6, d = i & 63;
      tq[l][d] = __builtin_nontemporal_load(q + ib + i);
      tk[l][d] = __builtin_nontemporal_load(k + ib + i);
    }
    __syncthreads();
    const size_t ob = (size_t)bh * DDIM * LSEQ + (size_t)chunk * 64;
    #pragma unroll
    for (int sp = 0; sp < 16; ++sp) {
      int o = t + sp * 256;
      int d = o >> 6, l = o & 63;
      qT[ob + (size_t)d * LSEQ + l] = tq[l][d];
      kT[ob + (size_t)d * LSEQ + l] = tk[l][d];
    }
  } else {
    // v -> fp16: bid' = xcd + 8*s, s in [0,128): bh = 2*xcd + (s>>6)
    const int b = blockIdx.x - 512;
    const int xcd = b & 7, s = b >> 3;
    const int bh = 2 * xcd + (s >> 6), inner = s & 63;
    const size_t base = ((size_t)bh * 64 + inner) * 2048 + (size_t)t * 8;
    f32x4 a0 = __builtin_nontemporal_load((const f32x4*)(v + base));
    f32x4 a1 = __builtin_nontemporal_load((const f32x4*)(v + base) + 1);
    __half h[8] = {__float2half(a0.x), __float2half(a0.y), __float2half(a0.z),
                   __float2half(a0.w), __float2half(a1.x), __float2half(a1.y),
                   __float2half(a1.z), __float2half(a1.w)};
    *(f32x4*)(v16 + base) = *(const f32x4*)h;   // 16B store of 8 halves
  }
}

#define CSWP(a, x, y, up) \
  { if ((a[x] > a[y]) == (up)) { auto _t = a[x]; a[x] = a[y]; a[y] = _t; } }

// full bitonic sort of 8 contiguous elems (base index 8*tt); u8 = dir for kk=8
__device__ __forceinline__ void sort8(unsigned long long* a, bool u8) {
  CSWP(a,0,1,true);  CSWP(a,2,3,false); CSWP(a,4,5,true);  CSWP(a,6,7,false);
  CSWP(a,0,2,true);  CSWP(a,1,3,true);  CSWP(a,4,6,false); CSWP(a,5,7,false);
  CSWP(a,0,1,true);  CSWP(a,2,3,true);  CSWP(a,4,5,false); CSWP(a,6,7,false);
  CSWP(a,0,4,u8); CSWP(a,1,5,u8); CSWP(a,2,6,u8); CSWP(a,3,7,u8);
  CSWP(a,0,2,u8); CSWP(a,1,3,u8); CSWP(a,4,6,u8); CSWP(a,5,7,u8);
  CSWP(a,0,1,u8); CSWP(a,2,3,u8); CSWP(a,4,5,u8); CSWP(a,6,7,u8);
}

// bitonic merge j=4,2,1 over 8 contiguous elems, uniform direction
__device__ __forceinline__ void merge8(unsigned long long* a, bool up) {
  CSWP(a,0,4,up); CSWP(a,1,5,up); CSWP(a,2,6,up); CSWP(a,3,7,up);
  CSWP(a,0,2,up); CSWP(a,1,3,up); CSWP(a,4,6,up); CSWP(a,5,7,up);
  CSWP(a,0,1,up); CSWP(a,2,3,up); CSWP(a,4,5,up); CSWP(a,6,7,up);
}

__device__ __forceinline__ unsigned long long bmin(unsigned long long a, unsigned long long b) {
  return a < b ? a : b;
}
__device__ __forceinline__ unsigned long long bmax(unsigned long long a, unsigned long long b) {
  return a > b ? a : b;
}

// Blocks [0, 1024): one 512-thr block per (b,h,d); threads 0-255 sort q,
// 256-511 sort k (identical 2048-elem network per half, tt = t & 255).
// Stages j<=4: in-register merge8. j=8,16: DPP quad_perm. j=32..256:
// __shfl_xor. j=512,1024: per-half 16KB LDS, one pass per stage.
// Emit: halves publish sorted keys in LDS; each half reads the other's
// rank-partner and issues its own entry type (8 scatter stores/thread).
// Blocks [1024, 1024+NPACKB): mask bit-pack (8 u64 words per block).
__global__ __launch_bounds__(SNTHR) void sort_emit_kernel(
    const float* __restrict__ qsrc, const float* __restrict__ ksrc,
    int stride, float* __restrict__ attn,
    const int* __restrict__ mask, unsigned long long* __restrict__ mbits) {
  const int bid = blockIdx.x;
  const int t = threadIdx.x;
  if (bid >= NBH * DDIM) {
    // ---- mask bit-pack tail-fill: word w = (bid-1024)*8 + wave
    const int w = (bid - NBH * DDIM) * 8 + (t >> 6);
    const int lane = t & 63;
    unsigned long long b = __ballot(mask[(size_t)w * 64 + lane] != 0);
    if (lane == 0) mbits[w] = b;
    return;
  }

  __shared__ unsigned long long sx[2][EPT][256];   // 32 KB
  const int lb  = (bid & 7) * (NBH * DDIM / 8) + (bid >> 3);  // XCD chunking
  const int bh = lb >> 6, d = lb & 63;
  const int half = t >> 8;          // 0 = q, 1 = k
  const int tt = t & 255;           // position within the half's network

  unsigned long long rr[EPT];
  if (stride == 1) {
    const float* sp = (half ? ksrc : qsrc) + ((size_t)bh * DDIM + d) * LSEQ;
    f32x4 a0 = __builtin_nontemporal_load((const f32x4*)sp + 2*tt);
    f32x4 a1 = __builtin_nontemporal_load((const f32x4*)sp + 2*tt + 1);
    float va[8] = {a0.x,a0.y,a0.z,a0.w,a1.x,a1.y,a1.z,a1.w};
    #pragma unroll
    for (int p = 0; p < 8; ++p) rr[p] = pack_kv(va[p], 8*tt + p);
  } else {
    const float* sp = half ? ksrc : qsrc;
    const size_t base = (size_t)bh * LSEQ * DDIM + d;
    #pragma unroll
    for (int p = 0; p < 8; ++p) {
      int l = 8*tt + p;
      rr[p] = pack_kv(sp[base + (size_t)l * DDIM], l);
    }
  }

  sort8(rr, (tt & 1) == 0);

  for (int kk = 16; kk <= LSEQ; kk <<= 1) {
    const bool up = (((8 * tt) & kk) == 0);
    // LDS stages: j >= 512; one pass, both halves exchange simultaneously.
    for (int j = kk >> 1; j >= 512; j >>= 1) {
      const int m = j >> 3;
      const int pt = tt ^ m;
      const bool ks = (((tt & m) == 0) == up);
      __syncthreads();
      #pragma unroll
      for (int p = 0; p < EPT; ++p) sx[half][p][tt] = rr[p];
      __syncthreads();
      #pragma unroll
      for (int p = 0; p < EPT; ++p) {
        unsigned long long a = sx[half][p][pt];
        rr[p] = ks ? bmin(rr[p], a) : bmax(rr[p], a);
      }
    }
    // shfl stages: 32 <= j <= 256 (m = j/8 in 4..32) on the DS pipe
    const int jstart = (kk >> 1) < 256 ? (kk >> 1) : 256;
    for (int j = jstart; j >= 32; j >>= 1) {
      const int m = j >> 3;
      const bool ks = (((tt & m) == 0) == up);
      #pragma unroll
      for (int p = 0; p < EPT; ++p) {
        unsigned long long a = __shfl_xor(rr[p], m);
        rr[p] = ks ? bmin(rr[p], a) : bmax(rr[p], a);
      }
    }
    // m=2 stage (j=16) via DPP quad_perm [2,3,0,1]
    if (kk >= 32) {
      const bool ks = (((tt & 2) == 0) == up);
      #pragma unroll
      for (int p = 0; p < EPT; ++p) {
        unsigned long long a = dpp_swap<0x4E>(rr[p]);
        rr[p] = ks ? bmin(rr[p], a) : bmax(rr[p], a);
      }
    }
    // m=1 stage (j=8) via DPP quad_perm [1,0,3,2]
    {
      const bool ks = (((tt & 1) == 0) == up);
      #pragma unroll
      for (int p = 0; p < EPT; ++p) {
        unsigned long long a = dpp_swap<0xB1>(rr[p]);
        rr[p] = ks ? bmin(rr[p], a) : bmax(rr[p], a);
      }
    }
    merge8(rr, up);
  }

  // publish sorted keys; each half reads the other's rank-partner and emits
  // its own entry type. entry = u16 col | fp16 weight. PLAIN stores (R10).
  __syncthreads();
  #pragma unroll
  for (int p = 0; p < EPT; ++p) sx[half][p][tt] = rr[p];
  __syncthreads();
  float* abh = attn + (size_t)bh * LSEQ * LSEQ;
  #pragma unroll
  for (int p = 0; p < EPT; ++p) {
    unsigned long long mine  = rr[p];
    unsigned long long other = sx[half ^ 1][p][tt];
    unsigned mi = (unsigned)(mine  & 0xffffffffu);
    unsigned oi = (unsigned)(other & 0xffffffffu);
    float mv = unpack_val(mine), ov = unpack_val(other);
    float diff = mv - ov;
    float w = __expf(-diff * diff) * (1.0f / (float)DDIM);
    unsigned hw = (unsigned)__half_as_ushort(__float2half(w));
    // half 0 (mine=q): direct entry, row qi, slot d.
    // half 1 (mine=k): transpose entry, row ki, slot 64+d.
    ((unsigned*)(abh + (size_t)mi * LSEQ))[(half << 6) + d] = oi | (hw << 16);
  }
}

__device__ __forceinline__ float half_bits_to_f32(unsigned bits) {
  return __half2float(__ushort_as_half((unsigned short)bits));
}

// One WAVE per attn row (128-thr blocks = 2 independent waves, NO
// __syncthreads -- all LDS state is per-wave, ordered by wave-local lgkmcnt).
// Phase order: entry load -> mask compaction -> matvec (loads only) -> out
// store -> densify + NT dense-row stores LAST.
// BITS path gathers v from the fp16 copy (halved L2 traffic, XCD-local).
template<bool BITS>
__global__ __launch_bounds__(128) void row_kernel(
    float* __restrict__ attn, const float* __restrict__ v,
    const __half* __restrict__ v16,
    const int* __restrict__ mask, const unsigned long long* __restrict__ mbits,
    float* __restrict__ out) {
  __shared__ float rowbuf[2][1024];
  __shared__ unsigned cent[2][136];              // compacted active entries
  __shared__ unsigned long long mb[2][32];
  const int wv = threadIdx.x >> 6, lane = threadIdx.x & 63;
  const int bid = blockIdx.x;
  const int lb = (bid & 7) * ((NBH * LSEQ / 2) / 8) + (bid >> 3);  // XCD chunking
  const int R = lb * 2 + wv;
  const int bh = R >> 11, r = R & (LSEQ - 1);
  float* arow = attn + (size_t)R * LSEQ;

  // phase 1: loads. Entry list = first 512B of this row's dense region.
  u32x2 ep = __builtin_nontemporal_load(((const u32x2*)arow) + lane);
  if (BITS && lane < 32) mb[wv][lane] = mbits[(size_t)r * 32 + lane];

  // phase 2: active tests + ballot compaction (lane holds entries 2l, 2l+1)
  const unsigned cA = ep.x & 0xFFFFu, cB = ep.y & 0xFFFFu;
  bool aA, aB;
  if (BITS) {
    LGKM0();
    aA = !((mb[wv][cA >> 6] >> (cA & 63)) & 1ull);
    aB = !((mb[wv][cB >> 6] >> (cB & 63)) & 1ull);
  } else {
    const int* mrow = mask + (size_t)r * LSEQ;
    aA = (mrow[cA] == 0);
    aB = (mrow[cB] == 0);
  }
  unsigned long long m0 = __ballot(aA), m1 = __ballot(aB);
  int n0 = __popcll(m0);
  int n  = n0 + __popcll(m1);
  if (aA) cent[wv][__popcll(m0 & ((1ull << lane) - 1ull))] = ep.x;
  if (aB) cent[wv][n0 + __popcll(m1 & ((1ull << lane) - 1ull))] = ep.y;
  int npad = (n + 7) & ~7;
  if (lane < npad - n) cent[wv][n + lane] = 0u;   // col 0, w = 0
  LGKM0();

  // phase 3: matvec over active entries only (pure loads, 8 accumulators)
  float acc[8];
  #pragma unroll
  for (int u = 0; u < 8; ++u) acc[u] = 0.0f;
  if (BITS) {
    const __half* vb = v16 + (size_t)bh * LSEQ * DDIM;
    for (int e = 0; e < npad; e += 8) {
      #pragma unroll
      for (int u = 0; u < 8; ++u) {
        unsigned en = cent[wv][e + u];
        acc[u] += half_bits_to_f32(en >> 16) *
                  __half2float(vb[(size_t)(en & 0xFFFFu) * DDIM + lane]);
      }
    }
  } else {
    const float* vb = v + (size_t)bh * LSEQ * DDIM;
    for (int e = 0; e < npad; e += 8) {
      #pragma unroll
      for (int u = 0; u < 8; ++u) {
        unsigned en = cent[wv][e + u];
        acc[u] += half_bits_to_f32(en >> 16) *
                  vb[(size_t)(en & 0xFFFFu) * DDIM + lane];
      }
    }
  }
  float s = ((acc[0] + acc[1]) + (acc[2] + acc[3])) +
            ((acc[4] + acc[5]) + (acc[6] + acc[7]));
  out[(size_t)R * DDIM + lane] = s;

  // phase 4: densify + dense-row NT stores (LAST; nothing waits on them)
  const float wA = half_bits_to_f32(ep.x >> 16);
  const float wB = half_bits_to_f32(ep.y >> 16);
  #pragma unroll
  for (int h = 0; h < 2; ++h) {
    f32x4 z = {0.0f, 0.0f, 0.0f, 0.0f};
    #pragma unroll
    for (int i = 0; i < 4; ++i) ((f32x4*)rowbuf[wv])[i * 64 + lane] = z;
    LGKM0();
    if ((int)(cA >> 10) == h) atomicAdd(&rowbuf[wv][cA & 1023], wA);
    if ((int)(cB >> 10) == h) atomicAdd(&rowbuf[wv][cB & 1023], wB);
    LGKM0();
    #pragma unroll
    for (int i = 0; i < 4; ++i) {
      f32x4 val = ((const f32x4*)rowbuf[wv])[i * 64 + lane];
      __builtin_nontemporal_store(val, ((f32x4*)(arow + (h << 10))) + i * 64 + lane);
    }
    LGKM0();   // rowbuf reads drained before next-half zeroing
  }
}

extern "C" void kernel_launch(void* const* d_in, const int* in_sizes, int n_in,
                              void* d_out, int out_size, void* d_ws, size_t ws_size,
                              hipStream_t stream) {
  const float* q = (const float*)d_in[0];
  const float* k = (const float*)d_in[1];
  const float* v = (const float*)d_in[2];
  const int* mask = (const int*)d_in[3];
  float* out = (float*)d_out;
  float* attn = out + (size_t)NBH * LSEQ * DDIM;

  const size_t qk_elems = (size_t)NBH * DDIM * LSEQ;        // 2M floats each
  const size_t qk_bytes = 2 * qk_elems * sizeof(float);     // 16 MiB
  const size_t mb_bytes = (size_t)LSEQ * (LSEQ / 64) * 8;   // 512 KiB
  const size_t v16_bytes = qk_elems * sizeof(__half);       // 4 MiB
  const bool has_full = ws_size >= qk_bytes + mb_bytes + v16_bytes;

  float* qT = (float*)d_ws;
  float* kT = qT + qk_elems;
  unsigned long long* mbits = (unsigned long long*)(kT + qk_elems);
  __half* v16 = (__half*)(mbits + LSEQ * (LSEQ / 64));

  if (has_full) {
    prep_kernel<<<512 + 1024, 256, 0, stream>>>(q, k, qT, kT, v, v16);
    sort_emit_kernel<<<NBH * DDIM + NPACKB, SNTHR, 0, stream>>>(
        qT, kT, 1, attn, mask, mbits);
    row_kernel<true><<<(NBH * LSEQ) / 2, 128, 0, stream>>>(
        attn, v, v16, nullptr, mbits, out);
  } else {
    sort_emit_kernel<<<NBH * DDIM, SNTHR, 0, stream>>>(
        q, k, DDIM, attn, mask, nullptr);
    row_kernel<false><<<(NBH * LSEQ) / 2, 128, 0, stream>>>(
        attn, v, nullptr, mask, nullptr, out);
  }
}

// Round 19
// 128.087 us; speedup vs baseline: 1.0089x; 1.0089x over previous
//
#include <hip/hip_runtime.h>
#include <hip/hip_fp16.h>

// Problem: B=2, H=8, L=2048, D=64.
// out0 = masked(p + p^T) @ v   (B,H,L,D)
// out1 = p + p^T               (B,H,L,L)
// p[b,h,qi,ki] += exp(-(q_sorted_r - k_sorted_r)^2)/D for rank-matched sorted
// q/k along L per (b,h,d). Each attn row receives exactly 64 direct + 64
// transpose entries (one per d) -> collision-free 4B slot per entry in the
// first 512B of each row's dense output region (u16 col | fp16 weight).
//
// R19 = R17 verbatim (best measured: 127.6us). R18's XCD-alignment + NT-load
// experiment regressed (+1.6us) -> reverted. Structure:
//   prep:      transpose q,k -> [bh][D][L]; v -> fp16 copy.
//   sort_emit: 512-thr blocks, threads 0-255 sort q / 256-511 sort k
//              (2048-elem bitonic, EPT=8, u64 keys; DPP quad_perm m=1,2;
//              shfl m=4..32; 1-pass LDS j>=512). Emit via LDS rank exchange,
//              plain scatter stores (L2 write-combined). Mask bit-pack rides
//              as grid tail-fill.
//   row:       per-wave: entry load -> bitmask compaction -> fp16-v gather
//              matvec -> densify -> NT dense-row stores.

#define LSEQ 2048
#define DDIM 64
#define NBH  16
#define SNTHR 512
#define EPT  8   // elements per thread (per half) in sort
#define NPACKB 8192   // mask-pack blocks appended to sort grid (8 words each)

typedef float    f32x4 __attribute__((ext_vector_type(4)));
typedef unsigned u32x2 __attribute__((ext_vector_type(2)));

#define LGKM0() asm volatile("s_waitcnt lgkmcnt(0)" ::: "memory")

__device__ __forceinline__ unsigned long long pack_kv(float f, unsigned idx) {
  unsigned u = __float_as_uint(f);
  u = (u & 0x80000000u) ? ~u : (u | 0x80000000u);   // sortable-ascending
  return ((unsigned long long)u << 32) | idx;
}

__device__ __forceinline__ float unpack_val(unsigned long long p) {
  unsigned us = (unsigned)(p >> 32);
  unsigned u = (us & 0x80000000u) ? (us & 0x7fffffffu) : ~us;
  return __uint_as_float(u);
}

// lane-xor-1 / lane-xor-2 exchange via DPP quad_perm (VALU, no DS pipe).
template<int CTRL>
__device__ __forceinline__ unsigned long long dpp_swap(unsigned long long x) {
  int lo = __builtin_amdgcn_update_dpp(0, (int)(unsigned)x,         CTRL, 0xF, 0xF, true);
  int hi = __builtin_amdgcn_update_dpp(0, (int)(unsigned)(x >> 32), CTRL, 0xF, 0xF, true);
  return ((unsigned long long)(unsigned)hi << 32) | (unsigned)lo;
}

// ---- prep: blocks [0,512) transpose q,k -> [bh][D][L];
//      blocks [512, 512+1024) convert v f32 -> fp16 (2048 elems each)
__global__ __launch_bounds__(256) void prep_kernel(
    const float* __restrict__ q, const float* __restrict__ k,
    float* __restrict__ qT, float* __restrict__ kT,
    const float* __restrict__ v, __half* __restrict__ v16) {
  const int t = threadIdx.x;
  if (blockIdx.x < 512) {
    __shared__ float tq[64][65], tk[64][65];
    const int bh = blockIdx.x >> 5, chunk = blockIdx.x & 31;
    const size_t ib = (size_t)bh * LSEQ * DDIM + (size_t)chunk * 64 * DDIM;
    #pragma unroll
    for (int s = 0; s < 16; ++s) {
      int i = t + s * 256;              // 64(l) x 64(d) tile
      int l = i >> 6, d = i & 63;
      tq[l][d] = q[ib + i];
      tk[l][d] = k[ib + i];
    }
    __syncthreads();
    const size_t ob = (size_t)bh * DDIM * LSEQ + (size_t)chunk * 64;
    #pragma unroll
    for (int s = 0; s < 16; ++s) {
      int o = t + s * 256;
      int d = o >> 6, l = o & 63;
      qT[ob + (size_t)d * LSEQ + l] = tq[l][d];
      kT[ob + (size_t)d * LSEQ + l] = tk[l][d];
    }
  } else {
    // v -> fp16: 2048 contiguous elems per block (8 per thread)
    const size_t base = (size_t)(blockIdx.x - 512) * 2048 + (size_t)t * 8;
    f32x4 a0 = *(const f32x4*)(v + base);
    f32x4 a1 = *(const f32x4*)(v + base + 4);
    __half h[8] = {__float2half(a0.x), __float2half(a0.y), __float2half(a0.z),
                   __float2half(a0.w), __float2half(a1.x), __float2half(a1.y),
                   __float2half(a1.z), __float2half(a1.w)};
    *(f32x4*)(v16 + base) = *(const f32x4*)h;   // 16B store of 8 halves
  }
}

#define CSWP(a, x, y, up) \
  { if ((a[x] > a[y]) == (up)) { auto _t = a[x]; a[x] = a[y]; a[y] = _t; } }

// full bitonic sort of 8 contiguous elems (base index 8*tt); u8 = dir for kk=8
__device__ __forceinline__ void sort8(unsigned long long* a, bool u8) {
  CSWP(a,0,1,true);  CSWP(a,2,3,false); CSWP(a,4,5,true);  CSWP(a,6,7,false);
  CSWP(a,0,2,true);  CSWP(a,1,3,true);  CSWP(a,4,6,false); CSWP(a,5,7,false);
  CSWP(a,0,1,true);  CSWP(a,2,3,true);  CSWP(a,4,5,false); CSWP(a,6,7,false);
  CSWP(a,0,4,u8); CSWP(a,1,5,u8); CSWP(a,2,6,u8); CSWP(a,3,7,u8);
  CSWP(a,0,2,u8); CSWP(a,1,3,u8); CSWP(a,4,6,u8); CSWP(a,5,7,u8);
  CSWP(a,0,1,u8); CSWP(a,2,3,u8); CSWP(a,4,5,u8); CSWP(a,6,7,u8);
}

// bitonic merge j=4,2,1 over 8 contiguous elems, uniform direction
__device__ __forceinline__ void merge8(unsigned long long* a, bool up) {
  CSWP(a,0,4,up); CSWP(a,1,5,up); CSWP(a,2,6,up); CSWP(a,3,7,up);
  CSWP(a,0,2,up); CSWP(a,1,3,up); CSWP(a,4,6,up); CSWP(a,5,7,up);
  CSWP(a,0,1,up); CSWP(a,2,3,up); CSWP(a,4,5,up); CSWP(a,6,7,up);
}

__device__ __forceinline__ unsigned long long bmin(unsigned long long a, unsigned long long b) {
  return a < b ? a : b;
}
__device__ __forceinline__ unsigned long long bmax(unsigned long long a, unsigned long long b) {
  return a > b ? a : b;
}

// Blocks [0, 1024): one 512-thr block per (b,h,d); threads 0-255 sort q,
// 256-511 sort k (identical 2048-elem network per half, tt = t & 255).
// Stages j<=4: in-register merge8. j=8,16: DPP quad_perm. j=32..256:
// __shfl_xor. j=512,1024: per-half 16KB LDS, one pass per stage.
// Emit: halves publish sorted keys in LDS; each half reads the other's
// rank-partner and issues its own entry type (8 scatter stores/thread).
// Blocks [1024, 1024+NPACKB): mask bit-pack (8 u64 words per block).
__global__ __launch_bounds__(SNTHR) void sort_emit_kernel(
    const float* __restrict__ qsrc, const float* __restrict__ ksrc,
    int stride, float* __restrict__ attn,
    const int* __restrict__ mask, unsigned long long* __restrict__ mbits) {
  const int bid = blockIdx.x;
  const int t = threadIdx.x;
  if (bid >= NBH * DDIM) {
    // ---- mask bit-pack tail-fill: word w = (bid-1024)*8 + wave
    const int w = (bid - NBH * DDIM) * 8 + (t >> 6);
    const int lane = t & 63;
    unsigned long long b = __ballot(mask[(size_t)w * 64 + lane] != 0);
    if (lane == 0) mbits[w] = b;
    return;
  }

  __shared__ unsigned long long sx[2][EPT][256];   // 32 KB
  const int lb  = (bid & 7) * (NBH * DDIM / 8) + (bid >> 3);  // XCD chunking
  const int bh = lb >> 6, d = lb & 63;
  const int half = t >> 8;          // 0 = q, 1 = k
  const int tt = t & 255;           // position within the half's network

  unsigned long long rr[EPT];
  if (stride == 1) {
    const float* sp = (half ? ksrc : qsrc) + ((size_t)bh * DDIM + d) * LSEQ;
    f32x4 a0 = ((const f32x4*)sp)[2*tt], a1 = ((const f32x4*)sp)[2*tt+1];
    float va[8] = {a0.x,a0.y,a0.z,a0.w,a1.x,a1.y,a1.z,a1.w};
    #pragma unroll
    for (int p = 0; p < 8; ++p) rr[p] = pack_kv(va[p], 8*tt + p);
  } else {
    const float* sp = half ? ksrc : qsrc;
    const size_t base = (size_t)bh * LSEQ * DDIM + d;
    #pragma unroll
    for (int p = 0; p < 8; ++p) {
      int l = 8*tt + p;
      rr[p] = pack_kv(sp[base + (size_t)l * DDIM], l);
    }
  }

  sort8(rr, (tt & 1) == 0);

  for (int kk = 16; kk <= LSEQ; kk <<= 1) {
    const bool up = (((8 * tt) & kk) == 0);
    // LDS stages: j >= 512; one pass, both halves exchange simultaneously.
    for (int j = kk >> 1; j >= 512; j >>= 1) {
      const int m = j >> 3;
      const int pt = tt ^ m;
      const bool ks = (((tt & m) == 0) == up);
      __syncthreads();
      #pragma unroll
      for (int p = 0; p < EPT; ++p) sx[half][p][tt] = rr[p];
      __syncthreads();
      #pragma unroll
      for (int p = 0; p < EPT; ++p) {
        unsigned long long a = sx[half][p][pt];
        rr[p] = ks ? bmin(rr[p], a) : bmax(rr[p], a);
      }
    }
    // shfl stages: 32 <= j <= 256 (m = j/8 in 4..32) on the DS pipe
    const int jstart = (kk >> 1) < 256 ? (kk >> 1) : 256;
    for (int j = jstart; j >= 32; j >>= 1) {
      const int m = j >> 3;
      const bool ks = (((tt & m) == 0) == up);
      #pragma unroll
      for (int p = 0; p < EPT; ++p) {
        unsigned long long a = __shfl_xor(rr[p], m);
        rr[p] = ks ? bmin(rr[p], a) : bmax(rr[p], a);
      }
    }
    // m=2 stage (j=16) via DPP quad_perm [2,3,0,1]
    if (kk >= 32) {
      const bool ks = (((tt & 2) == 0) == up);
      #pragma unroll
      for (int p = 0; p < EPT; ++p) {
        unsigned long long a = dpp_swap<0x4E>(rr[p]);
        rr[p] = ks ? bmin(rr[p], a) : bmax(rr[p], a);
      }
    }
    // m=1 stage (j=8) via DPP quad_perm [1,0,3,2]
    {
      const bool ks = (((tt & 1) == 0) == up);
      #pragma unroll
      for (int p = 0; p < EPT; ++p) {
        unsigned long long a = dpp_swap<0xB1>(rr[p]);
        rr[p] = ks ? bmin(rr[p], a) : bmax(rr[p], a);
      }
    }
    merge8(rr, up);
  }

  // publish sorted keys; each half reads the other's rank-partner and emits
  // its own entry type. entry = u16 col | fp16 weight. PLAIN stores (R10).
  __syncthreads();
  #pragma unroll
  for (int p = 0; p < EPT; ++p) sx[half][p][tt] = rr[p];
  __syncthreads();
  float* abh = attn + (size_t)bh * LSEQ * LSEQ;
  #pragma unroll
  for (int p = 0; p < EPT; ++p) {
    unsigned long long mine  = rr[p];
    unsigned long long other = sx[half ^ 1][p][tt];
    unsigned mi = (unsigned)(mine  & 0xffffffffu);
    unsigned oi = (unsigned)(other & 0xffffffffu);
    float mv = unpack_val(mine), ov = unpack_val(other);
    float diff = mv - ov;
    float w = __expf(-diff * diff) * (1.0f / (float)DDIM);
    unsigned hw = (unsigned)__half_as_ushort(__float2half(w));
    // half 0 (mine=q): direct entry, row qi, slot d.
    // half 1 (mine=k): transpose entry, row ki, slot 64+d.
    ((unsigned*)(abh + (size_t)mi * LSEQ))[(half << 6) + d] = oi | (hw << 16);
  }
}

__device__ __forceinline__ float half_bits_to_f32(unsigned bits) {
  return __half2float(__ushort_as_half((unsigned short)bits));
}

// One WAVE per attn row (128-thr blocks = 2 independent waves, NO
// __syncthreads -- all LDS state is per-wave, ordered by wave-local lgkmcnt).
// Phase order: entry load -> mask compaction -> matvec (loads only) -> out
// store -> densify + NT dense-row stores LAST.
// BITS path gathers v from the fp16 copy (halved L2 traffic).
template<bool BITS>
__global__ __launch_bounds__(128) void row_kernel(
    float* __restrict__ attn, const float* __restrict__ v,
    const __half* __restrict__ v16,
    const int* __restrict__ mask, const unsigned long long* __restrict__ mbits,
    float* __restrict__ out) {
  __shared__ float rowbuf[2][1024];
  __shared__ unsigned cent[2][136];              // compacted active entries
  __shared__ unsigned long long mb[2][32];
  const int wv = threadIdx.x >> 6, lane = threadIdx.x & 63;
  const int bid = blockIdx.x;
  const int lb = (bid & 7) * ((NBH * LSEQ / 2) / 8) + (bid >> 3);  // XCD chunking
  const int R = lb * 2 + wv;
  const int bh = R >> 11, r = R & (LSEQ - 1);
  float* arow = attn + (size_t)R * LSEQ;

  // phase 1: loads. Entry list = first 512B of this row's dense region.
  u32x2 ep = __builtin_nontemporal_load(((const u32x2*)arow) + lane);
  if (BITS && lane < 32) mb[wv][lane] = mbits[(size_t)r * 32 + lane];

  // phase 2: active tests + ballot compaction (lane holds entries 2l, 2l+1)
  const unsigned cA = ep.x & 0xFFFFu, cB = ep.y & 0xFFFFu;
  bool aA, aB;
  if (BITS) {
    LGKM0();
    aA = !((mb[wv][cA >> 6] >> (cA & 63)) & 1ull);
    aB = !((mb[wv][cB >> 6] >> (cB & 63)) & 1ull);
  } else {
    const int* mrow = mask + (size_t)r * LSEQ;
    aA = (mrow[cA] == 0);
    aB = (mrow[cB] == 0);
  }
  unsigned long long m0 = __ballot(aA), m1 = __ballot(aB);
  int n0 = __popcll(m0);
  int n  = n0 + __popcll(m1);
  if (aA) cent[wv][__popcll(m0 & ((1ull << lane) - 1ull))] = ep.x;
  if (aB) cent[wv][n0 + __popcll(m1 & ((1ull << lane) - 1ull))] = ep.y;
  int npad = (n + 7) & ~7;
  if (lane < npad - n) cent[wv][n + lane] = 0u;   // col 0, w = 0
  LGKM0();

  // phase 3: matvec over active entries only (pure loads, 8 accumulators)
  float acc[8];
  #pragma unroll
  for (int u = 0; u < 8; ++u) acc[u] = 0.0f;
  if (BITS) {
    const __half* vb = v16 + (size_t)bh * LSEQ * DDIM;
    for (int e = 0; e < npad; e += 8) {
      #pragma unroll
      for (int u = 0; u < 8; ++u) {
        unsigned en = cent[wv][e + u];
        acc[u] += half_bits_to_f32(en >> 16) *
                  __half2float(vb[(size_t)(en & 0xFFFFu) * DDIM + lane]);
      }
    }
  } else {
    const float* vb = v + (size_t)bh * LSEQ * DDIM;
    for (int e = 0; e < npad; e += 8) {
      #pragma unroll
      for (int u = 0; u < 8; ++u) {
        unsigned en = cent[wv][e + u];
        acc[u] += half_bits_to_f32(en >> 16) *
                  vb[(size_t)(en & 0xFFFFu) * DDIM + lane];
      }
    }
  }
  float s = ((acc[0] + acc[1]) + (acc[2] + acc[3])) +
            ((acc[4] + acc[5]) + (acc[6] + acc[7]));
  out[(size_t)R * DDIM + lane] = s;

  // phase 4: densify + dense-row NT stores (LAST; nothing waits on them)
  const float wA = half_bits_to_f32(ep.x >> 16);
  const float wB = half_bits_to_f32(ep.y >> 16);
  #pragma unroll
  for (int h = 0; h < 2; ++h) {
    f32x4 z = {0.0f, 0.0f, 0.0f, 0.0f};
    #pragma unroll
    for (int i = 0; i < 4; ++i) ((f32x4*)rowbuf[wv])[i * 64 + lane] = z;
    LGKM0();
    if ((int)(cA >> 10) == h) atomicAdd(&rowbuf[wv][cA & 1023], wA);
    if ((int)(cB >> 10) == h) atomicAdd(&rowbuf[wv][cB & 1023], wB);
    LGKM0();
    #pragma unroll
    for (int i = 0; i < 4; ++i) {
      f32x4 val = ((const f32x4*)rowbuf[wv])[i * 64 + lane];
      __builtin_nontemporal_store(val, ((f32x4*)(arow + (h << 10))) + i * 64 + lane);
    }
    LGKM0();   // rowbuf reads drained before next-half zeroing
  }
}

extern "C" void kernel_launch(void* const* d_in, const int* in_sizes, int n_in,
                              void* d_out, int out_size, void* d_ws, size_t ws_size,
                              hipStream_t stream) {
  const float* q = (const float*)d_in[0];
  const float* k = (const float*)d_in[1];
  const float* v = (const float*)d_in[2];
  const int* mask = (const int*)d_in[3];
  float* out = (float*)d_out;
  float* attn = out + (size_t)NBH * LSEQ * DDIM;

  const size_t qk_elems = (size_t)NBH * DDIM * LSEQ;        // 2M floats each
  const size_t qk_bytes = 2 * qk_elems * sizeof(float);     // 16 MiB
  const size_t mb_bytes = (size_t)LSEQ * (LSEQ / 64) * 8;   // 512 KiB
  const size_t v16_bytes = qk_elems * sizeof(__half);       // 4 MiB
  const bool has_full = ws_size >= qk_bytes + mb_bytes + v16_bytes;

  float* qT = (float*)d_ws;
  float* kT = qT + qk_elems;
  unsigned long long* mbits = (unsigned long long*)(kT + qk_elems);
  __half* v16 = (__half*)(mbits + LSEQ * (LSEQ / 64));

  if (has_full) {
    prep_kernel<<<512 + 1024, 256, 0, stream>>>(q, k, qT, kT, v, v16);
    sort_emit_kernel<<<NBH * DDIM + NPACKB, SNTHR, 0, stream>>>(
        qT, kT, 1, attn, mask, mbits);
    row_kernel<true><<<(NBH * LSEQ) / 2, 128, 0, stream>>>(
        attn, v, v16, nullptr, mbits, out);
  } else {
    sort_emit_kernel<<<NBH * DDIM, SNTHR, 0, stream>>>(
        q, k, DDIM, attn, mask, nullptr);
    row_kernel<false><<<(NBH * LSEQ) / 2, 128, 0, stream>>>(
        attn, v, nullptr, mask, nullptr, out);
  }
}